// Round 1
// baseline (23654.448 us; speedup 1.0000x reference)
//
#include <hip/hip_runtime.h>
#include <hip/hip_cooperative_groups.h>

namespace cg = cooperative_groups;

#define BN  64   // batch
#define TN  512  // time steps
#define INN 128  // input dim (layer 0)
#define HN  512  // hidden dim
#define ON  128  // output dim

// ws layout (floats):
//   xT   [TN][INN][BN]  = 4,194,304
//   h0r  [2][HN][BN]    = 65,536      (layer-0 h ring)
//   h1r  [2][HN][BN]    = 65,536      (layer-1 h ring)
#define XT_FLOATS   (TN * INN * BN)
#define RING_FLOATS (2 * HN * BN)

__device__ __forceinline__ float sigm(float x) { return 1.f / (1.f + __expf(-x)); }
__device__ __forceinline__ float tanh_(float x) {
    float e = __expf(2.f * x);
    return 1.f - 2.f / (e + 1.f);
}

// x[b][t][d] -> xT[t][d][b]
__global__ void transpose_x(const float* __restrict__ x, float* __restrict__ xT) {
    int idx = blockIdx.x * 256 + threadIdx.x;          // < TN*INN*BN = 2^22
    int b = idx & 63;
    int d = (idx >> 6) & 127;
    int t = idx >> 13;
    xT[idx] = x[((size_t)b * TN + t) * INN + d];
}

// Accumulate acc[r] += sum_{k in [k0,k1)} src[k][b] * w[r][colbase+k], r = 0..7
// src: global [K][BN]; wrow: LDS row-major [8][KT]
__device__ __forceinline__ void accum(const float* __restrict__ src,
                                      const float* wrow, int KT, int colbase,
                                      int k0, int k1, int b, float* acc) {
    for (int k = k0; k < k1; k += 4) {
        float x0 = src[(k + 0) * BN + b];
        float x1 = src[(k + 1) * BN + b];
        float x2 = src[(k + 2) * BN + b];
        float x3 = src[(k + 3) * BN + b];
#pragma unroll
        for (int r = 0; r < 8; ++r) {
            const float4 w4 = *(const float4*)(wrow + r * KT + colbase + k);
            acc[r] = fmaf(x0, w4.x, acc[r]);
            acc[r] = fmaf(x1, w4.y, acc[r]);
            acc[r] = fmaf(x2, w4.z, acc[r]);
            acc[r] = fmaf(x3, w4.w, acc[r]);
        }
    }
}

// Gate reduce + LSTM cell update for 2 hidden units x 64 batches (threads 0..127)
__device__ __forceinline__ void cell_update(float parts[4][8][BN], const float* bias,
                                            float cl[2][BN], float* __restrict__ hout,
                                            int wg, int tid) {
    int jj = tid >> 6, bb = tid & 63;
    float g[4];
#pragma unroll
    for (int gt = 0; gt < 4; ++gt) {
        int r = gt * 2 + jj;
        g[gt] = bias[r] + parts[0][r][bb] + parts[1][r][bb] + parts[2][r][bb] + parts[3][r][bb];
    }
    float c = sigm(g[1]) * cl[jj][bb] + sigm(g[0]) * tanh_(g[2]);
    cl[jj][bb] = c;
    hout[(2 * wg + jj) * BN + bb] = sigm(g[3]) * tanh_(c);
}

// Persistent cooperative kernel: both LSTM layers, software-pipelined.
// Grid step s: layer0 computes step s (s<TN); layer1 computes step u=s-1 (s>=1).
// 256 WGs x 256 threads; WG w owns hidden units {2w, 2w+1} (8 gate rows) of BOTH layers.
__global__ __launch_bounds__(256) void lstm_both(
    const float* __restrict__ xT,
    const float* __restrict__ Wih0, const float* __restrict__ Whh0,
    const float* __restrict__ bih0, const float* __restrict__ bhh0,
    const float* __restrict__ Wih1, const float* __restrict__ Whh1,
    const float* __restrict__ bih1, const float* __restrict__ bhh1,
    float* __restrict__ h0r, float* __restrict__ h1r) {
    // rows r = gate*2 + jj; global gate row = gate*HN + (2*wg + jj)
    __shared__ __align__(16) float w0[8 * 640];    // [Wih0 row (128) | Whh0 row (512)]
    __shared__ __align__(16) float w1[8 * 1024];   // [Wih1 row (512) | Whh1 row (512)]
    __shared__ float parts[4][8][BN];              // per-wave partial gates
    __shared__ float c0[2][BN], c1[2][BN];         // persistent cell state
    __shared__ float bias0[8], bias1[8];

    const int tid = threadIdx.x;
    const int wg  = blockIdx.x;       // 0..255
    const int b   = tid & 63;
    const int wv  = tid >> 6;         // wave 0..3: K-dimension split

    for (int idx = tid; idx < 8 * 640; idx += 256) {
        int r = idx / 640, k = idx - r * 640;
        int grow = (r >> 1) * HN + 2 * wg + (r & 1);
        w0[idx] = (k < INN) ? Wih0[grow * INN + k] : Whh0[grow * HN + (k - INN)];
    }
    for (int idx = tid; idx < 8 * 1024; idx += 256) {
        int r = idx >> 10, k = idx & 1023;
        int grow = (r >> 1) * HN + 2 * wg + (r & 1);
        w1[idx] = (k < HN) ? Wih1[grow * HN + k] : Whh1[grow * HN + (k - HN)];
    }
    if (tid < 8) {
        int grow = (tid >> 1) * HN + 2 * wg + (tid & 1);
        bias0[tid] = bih0[grow] + bhh0[grow];
        bias1[tid] = bih1[grow] + bhh1[grow];
    }
    if (tid < 128) { c0[tid >> 6][tid & 63] = 0.f; c1[tid >> 6][tid & 63] = 0.f; }
    __syncthreads();

    cg::grid_group grid = cg::this_grid();

    for (int s = 0; s <= TN; ++s) {
        // ---------- layer 0, step s ----------
        if (s < TN) {
            float acc[8] = {0.f, 0.f, 0.f, 0.f, 0.f, 0.f, 0.f, 0.f};
            const float* xs = xT + (size_t)s * INN * BN;
            accum(xs, w0, 640, 0, wv * 32, wv * 32 + 32, b, acc);           // x part, K=128
            if (s > 0) {
                const float* hp = h0r + ((s - 1) & 1) * (HN * BN);
                accum(hp, w0, 640, INN, wv * 128, wv * 128 + 128, b, acc);  // h part, K=512
            }
#pragma unroll
            for (int r = 0; r < 8; ++r) parts[wv][r][b] = acc[r];
        }
        __syncthreads();
        if (s < TN && tid < 128)
            cell_update(parts, bias0, c0, h0r + (s & 1) * (HN * BN), wg, tid);
        __syncthreads();

        // ---------- layer 1, step u = s-1 ----------
        if (s >= 1) {
            const int u = s - 1;
            float acc[8] = {0.f, 0.f, 0.f, 0.f, 0.f, 0.f, 0.f, 0.f};
            const float* xs = h0r + (u & 1) * (HN * BN);                    // layer-0 h at step u
            accum(xs, w1, 1024, 0, wv * 128, wv * 128 + 128, b, acc);       // x part, K=512
            if (u > 0) {
                const float* hp = h1r + ((u - 1) & 1) * (HN * BN);
                accum(hp, w1, 1024, HN, wv * 128, wv * 128 + 128, b, acc);  // h part, K=512
            }
#pragma unroll
            for (int r = 0; r < 8; ++r) parts[wv][r][b] = acc[r];
        }
        __syncthreads();
        if (s >= 1 && tid < 128)
            cell_update(parts, bias1, c1, h1r + ((s - 1) & 1) * (HN * BN), wg, tid);

        if (s < TN) grid.sync();
    }
}

// out[b][o] = sum_k h1[k][b] * Wfc[o][k] + bfc[o];  h1 is [HN][BN] (transposed)
__global__ void fc_kernel(const float* __restrict__ h1,
                          const float* __restrict__ Wfc, const float* __restrict__ bfc,
                          float* __restrict__ out) {
    int o = blockIdx.x;               // 0..127
    int tid = threadIdx.x;
    int bb = tid & 63;
    int kq = tid >> 6;                // 0..3
    float p = 0.f;
    for (int k = kq * 128; k < kq * 128 + 128; ++k)
        p = fmaf(h1[k * BN + bb], Wfc[o * HN + k], p);
    __shared__ float red[4][BN];
    red[kq][bb] = p;
    __syncthreads();
    if (tid < 64)
        out[tid * ON + o] = bfc[o] + red[0][tid] + red[1][tid] + red[2][tid] + red[3][tid];
}

extern "C" void kernel_launch(void* const* d_in, const int* in_sizes, int n_in,
                              void* d_out, int out_size, void* d_ws, size_t ws_size,
                              hipStream_t stream) {
    const float* x    = (const float*)d_in[0];
    const float* Wih0 = (const float*)d_in[1];
    const float* Whh0 = (const float*)d_in[2];
    const float* bih0 = (const float*)d_in[3];
    const float* bhh0 = (const float*)d_in[4];
    const float* Wih1 = (const float*)d_in[5];
    const float* Whh1 = (const float*)d_in[6];
    const float* bih1 = (const float*)d_in[7];
    const float* bhh1 = (const float*)d_in[8];
    const float* Wfc  = (const float*)d_in[9];
    const float* bfc  = (const float*)d_in[10];

    float* ws  = (float*)d_ws;
    float* xT  = ws;
    float* h0r = ws + XT_FLOATS;
    float* h1r = h0r + RING_FLOATS;

    hipLaunchKernelGGL(transpose_x, dim3(XT_FLOATS / 256), dim3(256), 0, stream, x, xT);

    void* args[] = { &xT, &Wih0, &Whh0, &bih0, &bhh0, &Wih1, &Whh1, &bih1, &bhh1, &h0r, &h1r };
    hipLaunchCooperativeKernel((void*)lstm_both, dim3(256), dim3(256), args, 0, stream);

    // h at final step of layer 1 lives in ring slot (TN-1)&1 == 1
    hipLaunchKernelGGL(fc_kernel, dim3(ON), dim3(256), 0, stream,
                       h1r + (( (TN - 1) & 1 ) * HN * BN), Wfc, bfc, (float*)d_out);
}

// Round 3
// 7313.365 us; speedup vs baseline: 3.2344x; 3.2344x over previous
//
#include <hip/hip_runtime.h>
#include <stdint.h>

#define BN  64
#define TN  512
#define INN 128
#define HN  512
#define ON  128
#define NBLK 256
#define NTHR 512

// ---- ws layout (bytes) ----
// xh  : [TN][32 k4][64 b][4 dl] fp16            = 8,388,608
// h0h : [TN][128 k4][64 b][4 dl] fp16           = 33,554,432
// h1h : same                                    = 33,554,432
// w0p : [2048 rows][640 k] fp16 (Wih0|Whh0)     = 2,621,440
// w1p : [2048 rows][1024 k] fp16 (Wih1|Whh1)    = 4,194,304
// d0  : [TN+1][256] u32 flags                   = 525,312
// d1  : same                                    = 525,312
#define XH_OFF 0
#define H0_OFF (8388608)
#define H1_OFF (H0_OFF + 33554432)
#define W0_OFF (H1_OFF + 33554432)
#define W1_OFF (W0_OFF + 2621440)
#define D0_OFF (W1_OFF + 4194304)
#define D1_OFF (D0_OFF + 525312)

typedef _Float16 h2 __attribute__((ext_vector_type(2)));

__device__ __forceinline__ float fdot2f(uint32_t a, uint32_t b, float c) {
#if __has_builtin(__builtin_amdgcn_fdot2)
    return __builtin_amdgcn_fdot2(__builtin_bit_cast(h2, a), __builtin_bit_cast(h2, b), c, false);
#else
    h2 x = __builtin_bit_cast(h2, a), y = __builtin_bit_cast(h2, b);
    return c + (float)x[0]*(float)y[0] + (float)x[1]*(float)y[1];
#endif
}

__device__ __forceinline__ float sigm(float x) { return 1.f / (1.f + __expf(-x)); }
__device__ __forceinline__ float tanh_(float x) {
    float e = __expf(2.f * x);
    return 1.f - 2.f / (e + 1.f);
}
__device__ __forceinline__ uint32_t packh2(float a, float b) {
    union { _Float16 h[2]; uint32_t u; } z;
    z.h[0] = (_Float16)a; z.h[1] = (_Float16)b; return z.u;
}

// x[b][t][d] fp32 -> xh[t][d>>2][b][d&3] fp16. One block per t.
__global__ __launch_bounds__(256) void pack_x(const float* __restrict__ x,
                                              uint32_t* __restrict__ xh32) {
    __shared__ float tile[64][INN];
    const int t = blockIdx.x, tid = threadIdx.x;
#pragma unroll
    for (int i = 0; i < 32; ++i) {
        int idx = i * 256 + tid;                 // < 8192
        int b = idx >> 7, d = idx & 127;
        tile[b][d] = x[((size_t)b * TN + t) * INN + d];
    }
    __syncthreads();
#pragma unroll
    for (int i = 0; i < 16; ++i) {
        int id = i * 256 + tid;                  // < 4096 u32 per t
        int dlp = id & 1, b = (id >> 1) & 63, k4 = id >> 7;
        int d = k4 * 4 + 2 * dlp;
        xh32[(size_t)t * 4096 + id] = packh2(tile[b][d], tile[b][d + 1]);
    }
}

// Wih0[2048][128] | Whh0[2048][512] fp32 -> w0p[row][640] fp16 (u32-paired)
__global__ __launch_bounds__(256) void pack_w0(const float* __restrict__ Wih,
                                               const float* __restrict__ Whh,
                                               uint32_t* __restrict__ wp32) {
    int idx = blockIdx.x * 256 + threadIdx.x;    // < 2048*320
    int row = idx / 320, kp = idx - row * 320, k = 2 * kp;
    float a, bv;
    if (k < INN) { a = Wih[row * INN + k]; bv = Wih[row * INN + k + 1]; }
    else         { a = Whh[row * HN + k - INN]; bv = Whh[row * HN + k - INN + 1]; }
    wp32[idx] = packh2(a, bv);
}

// Wih1[2048][512] | Whh1[2048][512] fp32 -> w1p[row][1024] fp16
__global__ __launch_bounds__(256) void pack_w1(const float* __restrict__ Wih,
                                               const float* __restrict__ Whh,
                                               uint32_t* __restrict__ wp32) {
    int idx = blockIdx.x * 256 + threadIdx.x;    // < 2048*512
    int row = idx >> 9, kp = idx & 511, k = 2 * kp;
    float a, bv;
    if (k < HN) { a = Wih[row * HN + k]; bv = Wih[row * HN + k + 1]; }
    else        { a = Whh[row * HN + k - HN]; bv = Whh[row * HN + k - HN + 1]; }
    wp32[idx] = packh2(a, bv);
}

// Persistent kernel: 256 blocks x 512 threads, 1 block/CU.
// Block owns hidden units {2*blk, 2*blk+1} (8 gate rows) of both layers.
// Flag-synced over immutable fp16 history; no grid.sync, no cache invalidation.
__global__ __launch_bounds__(NTHR) void lstm_pipe(
    const uint2* __restrict__ xh, uint32_t* h0w, uint32_t* h1w,
    const uint16_t* __restrict__ w0p, const uint16_t* __restrict__ w1p,
    const float* __restrict__ bih0, const float* __restrict__ bhh0,
    const float* __restrict__ bih1, const float* __restrict__ bhh1,
    uint32_t* d0, uint32_t* d1) {
    __shared__ float parts0[8][8][BN];
    __shared__ float parts1[8][8][BN];
    __shared__ float c0s[2][BN], c1s[2][BN];
    __shared__ float bias0[8], bias1[8];

    const int tid = threadIdx.x;
    const int blk = blockIdx.x;
    const int b   = tid & 63;
    const int wvu = __builtin_amdgcn_readfirstlane(tid >> 6);   // wave 0..7 (uniform)

    if (tid < 8) {
        int grow = ((tid >> 1) << 9) + 2 * blk + (tid & 1);
        bias0[tid] = bih0[grow] + bhh0[grow];
        bias1[tid] = bih1[grow] + bhh1[grow];
    }
    if (tid < BN) { c0s[0][tid] = 0.f; c0s[1][tid] = 0.f; c1s[0][tid] = 0.f; c1s[1][tid] = 0.f; }

    const uint4* w0r[8]; const uint4* w1r[8];
#pragma unroll
    for (int r = 0; r < 8; ++r) {
        int grow = ((r >> 1) << 9) + 2 * blk + (r & 1);
        w0r[r] = (const uint4*)(w0p + (size_t)grow * 640);
        w1r[r] = (const uint4*)(w1p + (size_t)grow * 1024);
    }
    __syncthreads();

    const uint2* h0c = (const uint2*)h0w;
    const uint2* h1c = (const uint2*)h1w;

    for (int s = 0; s <= TN; ++s) {
        // ---- poll flags (wave 0): h0[s-1] and h1[s-2] fully published ----
        if (tid < 64) {
            if (s >= 1) {
                for (int c = 0; c < 4; ++c) {
                    uint32_t* f = d0 + (size_t)(s - 1) * NBLK + c * 64 + tid;
                    while (true) {
                        uint32_t v = __hip_atomic_load(f, __ATOMIC_RELAXED, __HIP_MEMORY_SCOPE_AGENT);
                        if (__all(v == 1u)) break;
                        __builtin_amdgcn_s_sleep(2);
                    }
                }
            }
            if (s >= 2) {
                for (int c = 0; c < 4; ++c) {
                    uint32_t* f = d1 + (size_t)(s - 2) * NBLK + c * 64 + tid;
                    while (true) {
                        uint32_t v = __hip_atomic_load(f, __ATOMIC_RELAXED, __HIP_MEMORY_SCOPE_AGENT);
                        if (__all(v == 1u)) break;
                        __builtin_amdgcn_s_sleep(2);
                    }
                }
            }
        }
        __atomic_signal_fence(__ATOMIC_ACQ_REL);
        __syncthreads();                                    // A

        // ---- L0 accumulate: gates0[s] partials, wave = k-split ----
        float acc[8] = {0.f,0.f,0.f,0.f,0.f,0.f,0.f,0.f};
        if (s < TN) {
            const uint2* xcell = xh + (size_t)s * 2048;
            const uint2* hcell = h0c + (size_t)(s - 1) * 8192;
            const int kg0 = wvu * 10;                       // uint4 (8k) groups, 80 total
#pragma unroll 2
            for (int g = 0; g < 10; ++g) {
                int kg = kg0 + g;
                const uint2* src; int c4;
                if (kg < 16) { src = xcell; c4 = kg * 2; }
                else { if (s == 0) continue; src = hcell; c4 = (kg - 16) * 2; }
                uint2 hA = src[(size_t)c4 * 64 + b];
                uint2 hB = src[(size_t)(c4 + 1) * 64 + b];
#pragma unroll
                for (int r = 0; r < 8; ++r) {
                    uint4 W = w0r[r][kg];
                    acc[r] = fdot2f(W.x, hA.x, acc[r]);
                    acc[r] = fdot2f(W.y, hA.y, acc[r]);
                    acc[r] = fdot2f(W.z, hB.x, acc[r]);
                    acc[r] = fdot2f(W.w, hB.y, acc[r]);
                }
            }
        }
#pragma unroll
        for (int r = 0; r < 8; ++r) parts0[wvu][r][b] = acc[r];
        __syncthreads();                                    // B

        // ---- wave 0: cell update L0 (batch=b); waves 1-7 continue to L1 ----
        if (tid < 64 && s < TN) {
            float hv[2];
#pragma unroll
            for (int u = 0; u < 2; ++u) {
                float g4[4];
#pragma unroll
                for (int gg = 0; gg < 4; ++gg) {
                    int r = gg * 2 + u;
                    float v = bias0[r];
#pragma unroll
                    for (int w = 0; w < 8; ++w) v += parts0[w][r][b];
                    g4[gg] = v;
                }
                float cc = sigm(g4[1]) * c0s[u][b] + sigm(g4[0]) * tanh_(g4[2]);
                c0s[u][b] = cc;
                hv[u] = sigm(g4[3]) * tanh_(cc);
            }
            uint32_t pk = packh2(hv[0], hv[1]);
            __hip_atomic_store(h0w + (size_t)s * 16384 + ((((blk >> 1) * 64) + b) << 1) + (blk & 1),
                               pk, __ATOMIC_RELAXED, __HIP_MEMORY_SCOPE_AGENT);
        }

        // ---- L1 accumulate: gates1[s-1] partials ----
        float acc1[8] = {0.f,0.f,0.f,0.f,0.f,0.f,0.f,0.f};
        if (s >= 1) {
            const bool useh1 = (wvu >= 4);
            if (!useh1 || s >= 2) {
                const uint2* src = useh1 ? (h1c + (size_t)(s - 2) * 8192)
                                         : (h0c + (size_t)(s - 1) * 8192);
                const int kgbase = (useh1 ? (wvu - 4) : wvu) * 16;  // slab-local uint4 idx
                const int kgrow  = useh1 ? 64 : 0;                   // row uint4 offset
#pragma unroll 2
                for (int g = 0; g < 16; ++g) {
                    int kgl = kgbase + g;
                    uint2 hA = src[(size_t)(kgl * 2) * 64 + b];
                    uint2 hB = src[(size_t)(kgl * 2 + 1) * 64 + b];
#pragma unroll
                    for (int r = 0; r < 8; ++r) {
                        uint4 W = w1r[r][kgrow + kgl];
                        acc1[r] = fdot2f(W.x, hA.x, acc1[r]);
                        acc1[r] = fdot2f(W.y, hA.y, acc1[r]);
                        acc1[r] = fdot2f(W.z, hB.x, acc1[r]);
                        acc1[r] = fdot2f(W.w, hB.y, acc1[r]);
                    }
                }
            }
        }
#pragma unroll
        for (int r = 0; r < 8; ++r) parts1[wvu][r][b] = acc1[r];
        __syncthreads();                                    // C (drains h0[s] stores too)
        if (tid == 0 && s < TN)
            __hip_atomic_store(d0 + (size_t)s * NBLK + blk, 1u,
                               __ATOMIC_RELEASE, __HIP_MEMORY_SCOPE_AGENT);

        // ---- wave 0: cell update L1 (step s-1) ----
        if (tid < 64 && s >= 1) {
            float hv[2];
#pragma unroll
            for (int u = 0; u < 2; ++u) {
                float g4[4];
#pragma unroll
                for (int gg = 0; gg < 4; ++gg) {
                    int r = gg * 2 + u;
                    float v = bias1[r];
#pragma unroll
                    for (int w = 0; w < 8; ++w) v += parts1[w][r][b];
                    g4[gg] = v;
                }
                float cc = sigm(g4[1]) * c1s[u][b] + sigm(g4[0]) * tanh_(g4[2]);
                c1s[u][b] = cc;
                hv[u] = sigm(g4[3]) * tanh_(cc);
            }
            uint32_t pk = packh2(hv[0], hv[1]);
            __hip_atomic_store(h1w + (size_t)(s - 1) * 16384 + ((((blk >> 1) * 64) + b) << 1) + (blk & 1),
                               pk, __ATOMIC_RELAXED, __HIP_MEMORY_SCOPE_AGENT);
        }
        __syncthreads();                                    // D (drains h1 stores)
        if (tid == 0 && s >= 1)
            __hip_atomic_store(d1 + (size_t)(s - 1) * NBLK + blk, 1u,
                               __ATOMIC_RELEASE, __HIP_MEMORY_SCOPE_AGENT);
    }
}

// out[b][o] = sum_k h1[511][k][b]*Wfc[o][k] + bfc[o]
__global__ __launch_bounds__(256) void fc_kernel(const uint16_t* __restrict__ h1h,
                                                 const float* __restrict__ Wfc,
                                                 const float* __restrict__ bfc,
                                                 float* __restrict__ out) {
    const int o = blockIdx.x, tid = threadIdx.x;
    const int bb = tid & 63, kq = tid >> 6;
    const _Float16* hp = (const _Float16*)h1h + (size_t)511 * 32768;
    float p = 0.f;
    for (int k = kq * 128; k < kq * 128 + 128; ++k)
        p = fmaf((float)hp[((size_t)(k >> 2) * 64 + bb) * 4 + (k & 3)], Wfc[o * HN + k], p);
    __shared__ float red[4][BN];
    red[kq][bb] = p;
    __syncthreads();
    if (tid < 64)
        out[tid * ON + o] = bfc[o] + red[0][tid] + red[1][tid] + red[2][tid] + red[3][tid];
}

extern "C" void kernel_launch(void* const* d_in, const int* in_sizes, int n_in,
                              void* d_out, int out_size, void* d_ws, size_t ws_size,
                              hipStream_t stream) {
    const float* x    = (const float*)d_in[0];
    const float* Wih0 = (const float*)d_in[1];
    const float* Whh0 = (const float*)d_in[2];
    const float* bih0 = (const float*)d_in[3];
    const float* bhh0 = (const float*)d_in[4];
    const float* Wih1 = (const float*)d_in[5];
    const float* Whh1 = (const float*)d_in[6];
    const float* bih1 = (const float*)d_in[7];
    const float* bhh1 = (const float*)d_in[8];
    const float* Wfc  = (const float*)d_in[9];
    const float* bfc  = (const float*)d_in[10];

    char* ws = (char*)d_ws;
    uint32_t* xh32 = (uint32_t*)(ws + XH_OFF);
    uint32_t* h0w  = (uint32_t*)(ws + H0_OFF);
    uint32_t* h1w  = (uint32_t*)(ws + H1_OFF);
    uint16_t* w0p  = (uint16_t*)(ws + W0_OFF);
    uint16_t* w1p  = (uint16_t*)(ws + W1_OFF);
    uint32_t* d0   = (uint32_t*)(ws + D0_OFF);
    uint32_t* d1   = (uint32_t*)(ws + D1_OFF);

    hipMemsetAsync(d0, 0, 2 * 525312, stream);   // d0 and d1 are adjacent

    hipLaunchKernelGGL(pack_x, dim3(TN), dim3(256), 0, stream, x, xh32);
    hipLaunchKernelGGL(pack_w0, dim3(2048 * 320 / 256), dim3(256), 0, stream, Wih0, Whh0, (uint32_t*)w0p);
    hipLaunchKernelGGL(pack_w1, dim3(2048 * 512 / 256), dim3(256), 0, stream, Wih1, Whh1, (uint32_t*)w1p);

    void* args[] = { &xh32, &h0w, &h1w, &w0p, &w1p,
                     &bih0, &bhh0, &bih1, &bhh1, &d0, &d1 };
    hipLaunchCooperativeKernel((void*)lstm_pipe, dim3(NBLK), dim3(NTHR), args, 0, stream);

    hipLaunchKernelGGL(fc_kernel, dim3(ON), dim3(256), 0, stream,
                       (uint16_t*)h1w, Wfc, bfc, (float*)d_out);
}

// Round 4
// 7167.029 us; speedup vs baseline: 3.3005x; 1.0204x over previous
//
#include <hip/hip_runtime.h>
#include <stdint.h>

#define TN 512
#define HN 512
#define BN 64

typedef _Float16 half8 __attribute__((ext_vector_type(8)));
typedef float floatx4 __attribute__((ext_vector_type(4)));

// ---- ws layout (bytes) ----
// xb  [512 t][4 kt][4 bt][64 lane][8 j] fp16   =  8,388,608   (x in B-frag tiles)
// h0b [512 t][16 kt][4 bt][64][8] fp16         = 33,554,432   (layer-0 h history, B-frag tiles)
// h1b same                                     = 33,554,432
// a0p [128 blk][20 kt][64 lane][8 j] fp16      =  2,621,440   (L0 A-frags: [Wih0|Whh0])
// a1p [128 blk][32 kt][64 lane][8 j] fp16      =  4,194,304   (L1 A-frags: [Wih1|Whh1])
// c0  [512][32] u32 (128B-strided counters)    =     65,536
// c1  same                                     =     65,536
#define XB_OFF  (0ULL)
#define H0_OFF  (8388608ULL)
#define H1_OFF  (41943040ULL)
#define A0_OFF  (75497472ULL)
#define A1_OFF  (78118912ULL)
#define C0_OFF  (82313216ULL)
#define C1_OFF  (82378752ULL)

__device__ __forceinline__ float sigm(float x) { return 1.f / (1.f + __expf(-x)); }
__device__ __forceinline__ float tanh_(float x) {
    float e = __expf(2.f * x);
    return 1.f - 2.f / (e + 1.f);
}

// x[b][t][d] fp32 -> B-frag tiles: xb[t][kt][bt][lane][j], elem = x[n= bt*16+(lane&15)][t][k= kt*32+(lane>>4)*8+j]
__global__ __launch_bounds__(256) void pack_x(const float* __restrict__ x, uint32_t* __restrict__ xb) {
    const int bx = blockIdx.x;                 // t*16 + kt*4 + bt
    const int t = bx >> 4, kt = (bx >> 2) & 3, bt = bx & 3;
    const int tid = threadIdx.x;
    const int jp = tid & 3, lane = tid >> 2;
    const int n = bt * 16 + (lane & 15);
    const int k = kt * 32 + (lane >> 4) * 8 + jp * 2;
    const float* src = x + ((size_t)n * TN + t) * 128 + k;
    union { _Float16 h[2]; uint32_t u; } z;
    z.h[0] = (_Float16)src[0]; z.h[1] = (_Float16)src[1];
    xb[((size_t)bx * 64 + lane) * 4 + jp] = z.u;
}

// W -> A-frags. Block rows ordered r = ui*4 + g (ui=unit-in-block, g=gate) so that
// C quad = ui, C reg = gate  ->  lane-local cell update.
// ap[b][kt][lane][j], elem = Wcat[grow = g*HN + b*4 + ui][k = kt*32 + (lane>>4)*8 + j]
__global__ __launch_bounds__(256) void pack_a(const float* __restrict__ Wih, const float* __restrict__ Whh,
                                              int kin, int nkt, uint32_t* __restrict__ ap) {
    const int bx = blockIdx.x;                 // b*nkt + kt
    const int b = bx / nkt, kt = bx - b * nkt;
    const int tid = threadIdx.x;
    const int jp = tid & 3, lane = tid >> 2;
    const int r = lane & 15, quad = lane >> 4;
    const int k = kt * 32 + quad * 8 + jp * 2;
    const int grow = (r & 3) * HN + b * 4 + (r >> 2);
    float v0, v1;
    if (k < kin) { v0 = Wih[(size_t)grow * kin + k];       v1 = Wih[(size_t)grow * kin + k + 1]; }
    else         { v0 = Whh[(size_t)grow * HN + k - kin];  v1 = Whh[(size_t)grow * HN + k - kin + 1]; }
    union { _Float16 h[2]; uint32_t u; } z;
    z.h[0] = (_Float16)v0; z.h[1] = (_Float16)v1;
    ap[((size_t)bx * 64 + lane) * 4 + jp] = z.u;
}

// Persistent kernel: 256 blocks x 512 threads (8 waves), 1 block/CU.
// Blocks 0-127: layer 0 (units 4b..4b+3). Blocks 128-255: layer 1.
// Wave w: bt = w&3 (batch tile), kh = w>>2 (K half). Weights live in VGPRs (A-frags).
__global__ __launch_bounds__(512, 2) void lstm_mfma(
    const uint4* __restrict__ xb, uint4* h0b, uint4* h1b,
    const uint4* __restrict__ a0p, const uint4* __restrict__ a1p,
    const float* __restrict__ bih0, const float* __restrict__ bhh0,
    const float* __restrict__ bih1, const float* __restrict__ bhh1,
    uint32_t* c0, uint32_t* c1)
{
    __shared__ float red[4][64][4];            // cross-kh C reduction
    const int tid  = threadIdx.x;
    const int l    = tid & 63;
    const int w    = __builtin_amdgcn_readfirstlane(tid >> 6);
    const int bt   = w & 3, kh = w >> 2;
    const int quad = l >> 4, nl = l & 15;
    const int blk  = blockIdx.x;
    const bool isL0 = (blk < 128);
    const int b    = isL0 ? blk : blk - 128;
    const int u0   = b * 4;

    float bias[4];
    {
        const float* bi = isL0 ? bih0 : bih1;
        const float* bh = isL0 ? bhh0 : bhh1;
#pragma unroll
        for (int g = 0; g < 4; ++g) {
            int grow = g * HN + u0 + quad;
            bias[g] = bi[grow] + bh[grow];
        }
    }
    float cst = 0.f;                           // cell state (kh==0 waves; lane=(ui=quad, nl), batch=bt*16+nl)

    // publish position for this block's 4 units (consecutive: u0..u0+3 -> 4 consecutive halfwords)
    const int ktp = u0 >> 5, kqp = (u0 >> 3) & 3, jb = u0 & 7;   // jb in {0,4} -> 8B aligned
    uint4* hout = isL0 ? h0b : h1b;
    uint32_t* cout = isL0 ? c0 : c1;

    if (isL0) {
        half8 A[10];
        {
            const uint4* ap = a0p + ((size_t)b * 20 + kh * 10) * 64 + l;
#pragma unroll
            for (int kk = 0; kk < 10; ++kk) A[kk] = __builtin_bit_cast(half8, ap[(size_t)kk * 64]);
        }
        for (int s = 0; s < TN; ++s) {
            if (s > 0) {
                while (__hip_atomic_load(c0 + (size_t)(s - 1) * 32, __ATOMIC_RELAXED, __HIP_MEMORY_SCOPE_AGENT) < 128u)
                    __builtin_amdgcn_s_sleep(1);
            }
            floatx4 ca = {0.f,0.f,0.f,0.f}, cb = {0.f,0.f,0.f,0.f};
            if (kh == 0) {
#pragma unroll
                for (int kk = 0; kk < 10; ++kk) {      // kt = kk: 0..3 = x, 4..9 = h0[s-1]
                    uint4 bv;
                    if (kk < 4) bv = xb[(((size_t)s * 4 + kk) * 4 + bt) * 64 + l];
                    else { if (s == 0) continue;
                           bv = h0b[(((size_t)(s - 1) * 16 + (kk - 4)) * 4 + bt) * 64 + l]; }
                    half8 B = __builtin_bit_cast(half8, bv);
                    if (kk & 1) cb = __builtin_amdgcn_mfma_f32_16x16x32_f16(A[kk], B, cb, 0, 0, 0);
                    else        ca = __builtin_amdgcn_mfma_f32_16x16x32_f16(A[kk], B, ca, 0, 0, 0);
                }
            } else if (s > 0) {
#pragma unroll
                for (int kk = 0; kk < 10; ++kk) {      // kt = 10+kk -> h0 tile kk+6
                    uint4 bv = h0b[(((size_t)(s - 1) * 16 + (kk + 6)) * 4 + bt) * 64 + l];
                    half8 B = __builtin_bit_cast(half8, bv);
                    if (kk & 1) cb = __builtin_amdgcn_mfma_f32_16x16x32_f16(A[kk], B, cb, 0, 0, 0);
                    else        ca = __builtin_amdgcn_mfma_f32_16x16x32_f16(A[kk], B, ca, 0, 0, 0);
                }
            }
            floatx4 acc = ca + cb;
            if (kh == 1) {
#pragma unroll
                for (int g = 0; g < 4; ++g) red[bt][l][g] = acc[g];
            }
            __syncthreads();                           // A: kh=1 partials visible
            if (kh == 0) {
                float gi = acc[0] + red[bt][l][0] + bias[0];
                float gf = acc[1] + red[bt][l][1] + bias[1];
                float gg = acc[2] + red[bt][l][2] + bias[2];
                float go = acc[3] + red[bt][l][3] + bias[3];
                float c = sigm(gf) * cst + sigm(gi) * tanh_(gg);
                cst = c;
                float h = sigm(go) * tanh_(c);
                union { _Float16 hf; uint16_t u; } cv; cv.hf = (_Float16)h;
                uint32_t myu = cv.u;
                uint32_t a32 = myu | (((uint32_t)__shfl_xor((int)myu, 16)) << 16);
                uint32_t h32 = (uint32_t)__shfl_xor((int)a32, 32);
                if (quad == 0) {
                    uint64_t val = (uint64_t)a32 | ((uint64_t)h32 << 32);
                    uint64_t* dst = (uint64_t*)((char*)hout +
                        ((((size_t)s * 16 + ktp) * 4 + bt) * 1024 + (kqp * 16 + nl) * 16 + jb * 2));
                    __hip_atomic_store(dst, val, __ATOMIC_RELAXED, __HIP_MEMORY_SCOPE_AGENT);
                }
            }
            __syncthreads();                           // B: drains h stores (vmcnt) + red WAR
            if (tid == 0)
                __hip_atomic_fetch_add(cout + (size_t)s * 32, 1u, __ATOMIC_RELEASE, __HIP_MEMORY_SCOPE_AGENT);
        }
    } else {
        half8 A[16];
        {
            const uint4* ap = a1p + ((size_t)b * 32 + kh * 16) * 64 + l;
#pragma unroll
            for (int kk = 0; kk < 16; ++kk) A[kk] = __builtin_bit_cast(half8, ap[(size_t)kk * 64]);
        }
        for (int s = 0; s < TN; ++s) {
            if (kh == 0) {
                while (__hip_atomic_load(c0 + (size_t)s * 32, __ATOMIC_RELAXED, __HIP_MEMORY_SCOPE_AGENT) < 128u)
                    __builtin_amdgcn_s_sleep(1);
            } else if (s > 0) {
                while (__hip_atomic_load(c1 + (size_t)(s - 1) * 32, __ATOMIC_RELAXED, __HIP_MEMORY_SCOPE_AGENT) < 128u)
                    __builtin_amdgcn_s_sleep(1);
            }
            floatx4 ca = {0.f,0.f,0.f,0.f}, cb = {0.f,0.f,0.f,0.f};
            if (kh == 0) {                             // K half 1: h0[s]
#pragma unroll
                for (int kk = 0; kk < 16; ++kk) {
                    uint4 bv = h0b[(((size_t)s * 16 + kk) * 4 + bt) * 64 + l];
                    half8 B = __builtin_bit_cast(half8, bv);
                    if (kk & 1) cb = __builtin_amdgcn_mfma_f32_16x16x32_f16(A[kk], B, cb, 0, 0, 0);
                    else        ca = __builtin_amdgcn_mfma_f32_16x16x32_f16(A[kk], B, ca, 0, 0, 0);
                }
            } else if (s > 0) {                        // K half 2: h1[s-1]
#pragma unroll
                for (int kk = 0; kk < 16; ++kk) {
                    uint4 bv = h1b[(((size_t)(s - 1) * 16 + kk) * 4 + bt) * 64 + l];
                    half8 B = __builtin_bit_cast(half8, bv);
                    if (kk & 1) cb = __builtin_amdgcn_mfma_f32_16x16x32_f16(A[kk], B, cb, 0, 0, 0);
                    else        ca = __builtin_amdgcn_mfma_f32_16x16x32_f16(A[kk], B, ca, 0, 0, 0);
                }
            }
            floatx4 acc = ca + cb;
            if (kh == 1) {
#pragma unroll
                for (int g = 0; g < 4; ++g) red[bt][l][g] = acc[g];
            }
            __syncthreads();
            if (kh == 0) {
                float gi = acc[0] + red[bt][l][0] + bias[0];
                float gf = acc[1] + red[bt][l][1] + bias[1];
                float gg = acc[2] + red[bt][l][2] + bias[2];
                float go = acc[3] + red[bt][l][3] + bias[3];
                float c = sigm(gf) * cst + sigm(gi) * tanh_(gg);
                cst = c;
                float h = sigm(go) * tanh_(c);
                union { _Float16 hf; uint16_t u; } cv; cv.hf = (_Float16)h;
                uint32_t myu = cv.u;
                uint32_t a32 = myu | (((uint32_t)__shfl_xor((int)myu, 16)) << 16);
                uint32_t h32 = (uint32_t)__shfl_xor((int)a32, 32);
                if (quad == 0) {
                    uint64_t val = (uint64_t)a32 | ((uint64_t)h32 << 32);
                    uint64_t* dst = (uint64_t*)((char*)hout +
                        ((((size_t)s * 16 + ktp) * 4 + bt) * 1024 + (kqp * 16 + nl) * 16 + jb * 2));
                    __hip_atomic_store(dst, val, __ATOMIC_RELAXED, __HIP_MEMORY_SCOPE_AGENT);
                }
            }
            __syncthreads();
            if (tid == 0)
                __hip_atomic_fetch_add(cout + (size_t)s * 32, 1u, __ATOMIC_RELEASE, __HIP_MEMORY_SCOPE_AGENT);
        }
    }
}

// out[n][o] = sum_k h1[T-1][k][n] * Wfc[o][k] + bfc[o]; h1 read from B-frag tile layout.
__global__ __launch_bounds__(256) void fc_kernel(const uint16_t* __restrict__ h1b,
                                                 const float* __restrict__ Wfc,
                                                 const float* __restrict__ bfc,
                                                 float* __restrict__ out) {
    const int o = blockIdx.x, tid = threadIdx.x;
    const int bb = tid & 63, kq = tid >> 6;
    float p = 0.f;
    for (int k = kq * 128; k < kq * 128 + 128; ++k) {
        size_t idx = ((((size_t)511 * 16 + (k >> 5)) * 4 + (bb >> 4)) * 64
                      + ((k >> 3) & 3) * 16 + (bb & 15)) * 8 + (k & 7);
        _Float16 hv = ((const _Float16*)h1b)[idx];
        p = fmaf((float)hv, Wfc[(size_t)o * HN + k], p);
    }
    __shared__ float red[4][64];
    red[kq][bb] = p;
    __syncthreads();
    if (tid < 64)
        out[(size_t)tid * 128 + o] = bfc[o] + red[0][tid] + red[1][tid] + red[2][tid] + red[3][tid];
}

extern "C" void kernel_launch(void* const* d_in, const int* in_sizes, int n_in,
                              void* d_out, int out_size, void* d_ws, size_t ws_size,
                              hipStream_t stream) {
    const float* x    = (const float*)d_in[0];
    const float* Wih0 = (const float*)d_in[1];
    const float* Whh0 = (const float*)d_in[2];
    const float* bih0 = (const float*)d_in[3];
    const float* bhh0 = (const float*)d_in[4];
    const float* Wih1 = (const float*)d_in[5];
    const float* Whh1 = (const float*)d_in[6];
    const float* bih1 = (const float*)d_in[7];
    const float* bhh1 = (const float*)d_in[8];
    const float* Wfc  = (const float*)d_in[9];
    const float* bfc  = (const float*)d_in[10];

    char* ws = (char*)d_ws;
    uint32_t* xb  = (uint32_t*)(ws + XB_OFF);
    uint4*    h0b = (uint4*)(ws + H0_OFF);
    uint4*    h1b = (uint4*)(ws + H1_OFF);
    uint32_t* a0p = (uint32_t*)(ws + A0_OFF);
    uint32_t* a1p = (uint32_t*)(ws + A1_OFF);
    uint32_t* c0  = (uint32_t*)(ws + C0_OFF);
    uint32_t* c1  = (uint32_t*)(ws + C1_OFF);

    hipMemsetAsync(c0, 0, 131072, stream);   // c0 + c1

    hipLaunchKernelGGL(pack_x, dim3(TN * 16), dim3(256), 0, stream, x, xb);
    hipLaunchKernelGGL(pack_a, dim3(128 * 20), dim3(256), 0, stream, Wih0, Whh0, 128, 20, a0p);
    hipLaunchKernelGGL(pack_a, dim3(128 * 32), dim3(256), 0, stream, Wih1, Whh1, 512, 32, a1p);

    const uint4* xbc = (const uint4*)xb;
    const uint4* a0c = (const uint4*)a0p;
    const uint4* a1c = (const uint4*)a1p;
    void* args[] = { &xbc, &h0b, &h1b, &a0c, &a1c,
                     &bih0, &bhh0, &bih1, &bhh1, &c0, &c1 };
    hipLaunchCooperativeKernel((void*)lstm_mfma, dim3(256), dim3(512), args, 0, stream);

    hipLaunchKernelGGL(fc_kernel, dim3(128), dim3(256), 0, stream,
                       (const uint16_t*)h1b, Wfc, bfc, (float*)d_out);
}